// Round 1
// baseline (544.601 us; speedup 1.0000x reference)
//
#include <hip/hip_runtime.h>

typedef unsigned short u16;
typedef __attribute__((ext_vector_type(8))) short short8;   // 8 bf16 = 4 VGPRs (MFMA A/B frag)
typedef __attribute__((ext_vector_type(4))) float f32x4;    // MFMA C/D frag

#define T_SEQ 8192
#define DDIM 1024
#define BB 4
#define MM (BB * T_SEQ)      // 32768
#define NC 128               // chunks along T
#define CHUNK (T_SEQ / NC)   // 64
#define CHAINS (BB * DDIM)   // 4096

// ---------- helpers ----------
__device__ __forceinline__ float bf_lo(unsigned p) {
    union { unsigned u; float f; } v; v.u = p << 16; return v.f;
}
__device__ __forceinline__ float bf_hi(unsigned p) {
    union { unsigned u; float f; } v; v.u = p & 0xffff0000u; return v.f;
}
__device__ __forceinline__ u16 f2bf(float f) {
    union { unsigned u; float f; } v; v.f = f;
    unsigned r = v.u + 0x7fffu + ((v.u >> 16) & 1u);   // RNE
    return (u16)(r >> 16);
}
__device__ __forceinline__ float sigm(float z) {
    return __builtin_amdgcn_rcpf(1.0f + __expf(-z));
}
__device__ __forceinline__ void gld16(const u16* g, u16* l) {
    __builtin_amdgcn_global_load_lds((const __attribute__((address_space(1))) void*)g,
                                     (__attribute__((address_space(3))) void*)l, 16, 0, 0);
}

// ---------- K1: fp32 -> bf16 convert (4 elems/thread) ----------
__global__ __launch_bounds__(256) void cvt_bf16(const float* __restrict__ src,
                                                u16* __restrict__ dst, int n4) {
    int i = blockIdx.x * 256 + threadIdx.x;
    if (i < n4) {
        float4 v = ((const float4*)src)[i];
        ushort4 o;
        o.x = f2bf(v.x); o.y = f2bf(v.y); o.z = f2bf(v.z); o.w = f2bf(v.w);
        ((ushort4*)dst)[i] = o;
    }
}

// ---------- K2: bf16 GEMM (m97 structure): gate = X @ W^T + b, bf16 out ----------
// X: [M][K] bf16, W: [N][K] bf16 (row-major = B^T gemm). Tile 128x128, BK=32,
// 256 threads = 4 waves in 2x2, each wave 64x64 via 4x4 frags of 16x16x32 MFMA.
__global__ __launch_bounds__(256, 2)
void gemm_gates(const u16* __restrict__ X, const u16* __restrict__ Wi,
                const u16* __restrict__ Wg, const float* __restrict__ b_in,
                const float* __restrict__ b_gate,
                u16* __restrict__ IG, u16* __restrict__ RG) {
    const int gate = blockIdx.z;
    const u16* __restrict__ Wp = gate ? Wg : Wi;
    const float* __restrict__ bias = gate ? b_gate : b_in;
    u16* __restrict__ outp = gate ? RG : IG;

    const int tN0 = blockIdx.x * 128;
    const int tM0 = blockIdx.y * 128;
    const int tid = threadIdx.x;
    const int lane = tid & 63;
    const int w = tid >> 6;
    const int wm = w >> 1, wn = w & 1;

    __shared__ u16 lA[128 * 32];
    __shared__ u16 lB[128 * 32];

    // staging: thread t loads 16B at tile elem t*8 (issue0) and 2048+t*8 (issue1)
    const u16* gA = X + (size_t)(tM0 + (tid >> 2)) * DDIM + (tid & 3) * 8;
    const u16* gB = Wp + (size_t)(tN0 + (tid >> 2)) * DDIM + (tid & 3) * 8;
    u16* lA0 = &lA[tid * 8];
    u16* lB0 = &lB[tid * 8];

    f32x4 acc[4][4] = {};

    const int lm = lane & 15;
    const int q8 = (lane >> 4) * 8;

    for (int k0 = 0; k0 < DDIM; k0 += 32) {
        __syncthreads();
        gld16(gA, lA0);
        gld16(gA + 64 * DDIM, lA0 + 2048);
        gld16(gB, lB0);
        gld16(gB + 64 * DDIM, lB0 + 2048);
        gA += 32; gB += 32;
        __syncthreads();

        short8 af[4], bfr[4];
#pragma unroll
        for (int i = 0; i < 4; i++)
            af[i] = *(const short8*)&lA[(wm * 64 + i * 16 + lm) * 32 + q8];
#pragma unroll
        for (int j = 0; j < 4; j++)
            bfr[j] = *(const short8*)&lB[(wn * 64 + j * 16 + lm) * 32 + q8];
#pragma unroll
        for (int i = 0; i < 4; i++)
#pragma unroll
            for (int j = 0; j < 4; j++)
                acc[i][j] = __builtin_amdgcn_mfma_f32_16x16x32_bf16(af[i], bfr[j], acc[i][j], 0, 0, 0);
    }

    // epilogue: C/D layout col=lane&15, row=(lane>>4)*4+reg
    const int r0 = (lane >> 4) << 2;
    const int cb = lane & 15;
#pragma unroll
    for (int j = 0; j < 4; j++) {
        const int colg = tN0 + wn * 64 + j * 16 + cb;
        const float bj = bias[colg];
#pragma unroll
        for (int i = 0; i < 4; i++) {
            const int rowb = tM0 + wm * 64 + i * 16 + r0;
#pragma unroll
            for (int r = 0; r < 4; r++)
                outp[(size_t)(rowb + r) * DDIM + colg] = f2bf(acc[i][j][r] + bj);
        }
    }
}

// ---------- gating math (shared by pass1/pass3) ----------
// alpha = exp(-8*softplus(lam)*sigmoid(rg)); beta = sqrt(1-alpha^2+1e-6);
// xbeta = beta*sigmoid(ig)*x
__device__ __forceinline__ void gate_eval(float nsp, float ig, float rg, float x,
                                          float& a, float& xb) {
    float sr = sigm(rg);
    a = __expf(nsp * sr);
    float be = sqrtf(1.0f - a * a + 1e-6f);
    xb = be * sigm(ig) * x;
}

// ---------- K3: pass1 — per-chunk aggregates (A = prod alpha, B = local scan end) ----------
__global__ __launch_bounds__(256)
void scan_pass1(const u16* __restrict__ IG, const u16* __restrict__ RG,
                const float* __restrict__ X, const float* __restrict__ lam,
                float* __restrict__ AggA, float* __restrict__ AggB) {
    const int c = blockIdx.x, dblk = blockIdx.y, b = blockIdx.z;
    const int d0 = dblk * 512 + threadIdx.x * 2;
    const float nsp0 = -8.0f * log1pf(__expf(lam[d0]));
    const float nsp1 = -8.0f * log1pf(__expf(lam[d0 + 1]));
    size_t base = ((size_t)(b * T_SEQ + c * CHUNK)) * DDIM + d0;

    float A0 = 1.0f, B0 = 0.0f, A1 = 1.0f, B1 = 0.0f;
#pragma unroll 4
    for (int t = 0; t < CHUNK; t++) {
        unsigned igp = *(const unsigned*)(IG + base);
        unsigned rgp = *(const unsigned*)(RG + base);
        float2 xv = *(const float2*)(X + base);
        float a0, xb0, a1, xb1;
        gate_eval(nsp0, bf_lo(igp), bf_lo(rgp), xv.x, a0, xb0);
        gate_eval(nsp1, bf_hi(igp), bf_hi(rgp), xv.y, a1, xb1);
        B0 = a0 * B0 + xb0; A0 *= a0;
        B1 = a1 * B1 + xb1; A1 *= a1;
        base += DDIM;
    }
    const int chain = b * DDIM + d0;
    float2 av; av.x = A0; av.y = A1;
    float2 bv; bv.x = B0; bv.y = B1;
    *(float2*)(AggA + (size_t)c * CHAINS + chain) = av;
    *(float2*)(AggB + (size_t)c * CHAINS + chain) = bv;
}

// ---------- K4: pass2 — serial scan over NC chunk aggregates per chain ----------
__global__ __launch_bounds__(256)
void scan_pass2(const float* __restrict__ AggA, const float* __restrict__ AggB,
                float* __restrict__ H0) {
    const int chain = blockIdx.x * 256 + threadIdx.x;   // 4096 chains
    float p = 0.0f;
    for (int c = 0; c < NC; c++) {
        H0[(size_t)c * CHAINS + chain] = p;
        p = AggA[(size_t)c * CHAINS + chain] * p + AggB[(size_t)c * CHAINS + chain];
    }
}

// ---------- K5: pass3 — apply chunk prefix, write h ----------
__global__ __launch_bounds__(256)
void scan_pass3(const u16* __restrict__ IG, const u16* __restrict__ RG,
                const float* __restrict__ X, const float* __restrict__ lam,
                const float* __restrict__ H0, float* __restrict__ out) {
    const int c = blockIdx.x, dblk = blockIdx.y, b = blockIdx.z;
    const int d0 = dblk * 512 + threadIdx.x * 2;
    const float nsp0 = -8.0f * log1pf(__expf(lam[d0]));
    const float nsp1 = -8.0f * log1pf(__expf(lam[d0 + 1]));
    size_t base = ((size_t)(b * T_SEQ + c * CHUNK)) * DDIM + d0;
    const int chain = b * DDIM + d0;

    float2 h = *(const float2*)(H0 + (size_t)c * CHAINS + chain);
#pragma unroll 4
    for (int t = 0; t < CHUNK; t++) {
        unsigned igp = *(const unsigned*)(IG + base);
        unsigned rgp = *(const unsigned*)(RG + base);
        float2 xv = *(const float2*)(X + base);
        float a0, xb0, a1, xb1;
        gate_eval(nsp0, bf_lo(igp), bf_lo(rgp), xv.x, a0, xb0);
        gate_eval(nsp1, bf_hi(igp), bf_hi(rgp), xv.y, a1, xb1);
        h.x = a0 * h.x + xb0;
        h.y = a1 * h.y + xb1;
        *(float2*)(out + base) = h;
        base += DDIM;
    }
}

// ---------- launch ----------
extern "C" void kernel_launch(void* const* d_in, const int* in_sizes, int n_in,
                              void* d_out, int out_size, void* d_ws, size_t ws_size,
                              hipStream_t stream) {
    const float* x   = (const float*)d_in[0];
    const float* Win = (const float*)d_in[1];
    const float* bin = (const float*)d_in[2];
    const float* Wg  = (const float*)d_in[3];
    const float* bg  = (const float*)d_in[4];
    const float* lam = (const float*)d_in[5];
    float* out = (float*)d_out;

    // workspace layout (MiB offsets): Wi_bf 0..2, Wg_bf 2..4, IG 4..68, RG 68..132,
    // AggA 132..134, AggB 134..136, H0 136..138   (needs 138 MiB)
    char* w = (char*)d_ws;
    u16* Wi_bf = (u16*)(w);
    u16* Wg_bf = (u16*)(w + (size_t)(2) * 1024 * 1024);
    u16* IG    = (u16*)(w + (size_t)(4) * 1024 * 1024);
    u16* RG    = (u16*)(w + (size_t)(68) * 1024 * 1024);
    float* AggA = (float*)(w + (size_t)(132) * 1024 * 1024);
    float* AggB = (float*)(w + (size_t)(134) * 1024 * 1024);
    float* H0   = (float*)(w + (size_t)(136) * 1024 * 1024);

    // x_bf16 staged in first 64 MiB of d_out (dead once GEMM completes;
    // pass3 overwrites d_out with h afterwards — stream-ordered, safe)
    u16* Xbf = (u16*)d_out;

    // K1: converts
    cvt_bf16<<<dim3((MM * DDIM / 4 + 255) / 256), dim3(256), 0, stream>>>(x, Xbf, MM * DDIM / 4);
    cvt_bf16<<<dim3((DDIM * DDIM / 4 + 255) / 256), dim3(256), 0, stream>>>(Win, Wi_bf, DDIM * DDIM / 4);
    cvt_bf16<<<dim3((DDIM * DDIM / 4 + 255) / 256), dim3(256), 0, stream>>>(Wg, Wg_bf, DDIM * DDIM / 4);

    // K2: both gate GEMMs (grid.z selects gate)
    gemm_gates<<<dim3(DDIM / 128, MM / 128, 2), dim3(256), 0, stream>>>(
        Xbf, Wi_bf, Wg_bf, bin, bg, IG, RG);

    // K3-K5: chunked scan
    scan_pass1<<<dim3(NC, 2, BB), dim3(256), 0, stream>>>(IG, RG, x, lam, AggA, AggB);
    scan_pass2<<<dim3(CHAINS / 256), dim3(256), 0, stream>>>(AggA, AggB, H0);
    scan_pass3<<<dim3(NC, 2, BB), dim3(256), 0, stream>>>(IG, RG, x, lam, H0, out);
}